// Round 3
// baseline (258.964 us; speedup 1.0000x reference)
//
#include <hip/hip_runtime.h>
#include <hip/hip_bf16.h>
#include <cstdint>
#include <cstddef>

// B=4, T=4096, C=1024, d=64 causal self-attention head.
// R6 (= R5 minus the stray label): proj_gemm is a pure-VGPR 3-slot software
//   pipeline (distance-3 prefetch, named register slots, static indices).
//   No LDS, no barriers: compiler emits counted vmcnt for register loads
//   (it only over-drains when LDS aliasing is involved -- the R4 failure).
//   1-wave blocks, grid 3072, __launch_bounds__(64,4).
// flash_split/pack_w/normalize unchanged from R4.

typedef __attribute__((ext_vector_type(8))) short short8;       // 8 x bf16 frag
typedef __attribute__((ext_vector_type(4))) float f32x4;
typedef __attribute__((ext_vector_type(4))) unsigned int uint4v;
typedef __attribute__((ext_vector_type(4))) unsigned short ushort4v;
typedef unsigned short ushort;

#define MFMA16x16x32(A,B,C) __builtin_amdgcn_mfma_f32_16x16x32_bf16((A),(B),(C),0,0,0)

static __device__ __forceinline__ unsigned pack2_bf16(float f0, float f1){
  unsigned u0 = __builtin_bit_cast(unsigned, f0) + 0x8000u;
  unsigned u1 = __builtin_bit_cast(unsigned, f1) + 0x8000u;
  return __builtin_amdgcn_perm(u1, u0, 0x07060302u);
}
static __device__ __forceinline__ unsigned short bf16u(float f){
  return (unsigned short)((__builtin_bit_cast(unsigned, f) + 0x8000u) >> 16);
}
static __device__ __forceinline__ short8 cvt8(f32x4 a, f32x4 b){
  union { unsigned u[4]; short8 s; } r;
  r.u[0] = pack2_bf16(a[0], a[1]);
  r.u[1] = pack2_bf16(a[2], a[3]);
  r.u[2] = pack2_bf16(b[0], b[1]);
  r.u[3] = pack2_bf16(b[2], b[3]);
  return r.s;
}
static __device__ __forceinline__ float fast_exp2(float x){
  float r; asm("v_exp_f32 %0, %1" : "=v"(r) : "v"(x)); return r;
}
static __device__ __forceinline__ float fast_rcp(float x){
  float r; asm("v_rcp_f32 %0, %1" : "=v"(r) : "v"(x)); return r;
}
static __device__ __forceinline__ void gl_lds16(const void* g, void* l){
  __builtin_amdgcn_global_load_lds(
      (const __attribute__((address_space(1))) void*)g,
      (__attribute__((address_space(3))) void*)l, 16, 0, 0);
}

// ---------------------------------------------------------------------------
// Kernel 0: pack W fp32 -> bf16 B-fragment layout; also zero out (4MB) + L.
// ---------------------------------------------------------------------------
__global__ __launch_bounds__(256) void pack_w(
    const float* __restrict__ Wq, const float* __restrict__ Wk,
    const float* __restrict__ Wv, unsigned short* __restrict__ Wp,
    float* __restrict__ out, float* __restrict__ Lbuf)
{
  int t = blockIdx.x * 256 + threadIdx.x;      // 256 blocks x 256 = 65536 thr
  if (t < 24576){                               // 3*32*4*64 pack jobs
    int lane = t & 63, nf = (t >> 6) & 3, cc = (t >> 8) & 31, p = t >> 13;
    int qd = lane >> 4, l = lane & 15;
    const float* W = (p == 0) ? Wq : ((p == 1) ? Wk : Wv);
    const float* src = W + (size_t)(cc * 32 + qd * 8) * 64 + nf * 16 + l;
    uint4v u;
    #pragma unroll
    for (int j = 0; j < 4; ++j)
      u[j] = pack2_bf16(src[(2 * j) * 64], src[(2 * j + 1) * 64]);
    *(uint4v*)(Wp + (size_t)t * 8) = u;
  }
  const f32x4 z = (f32x4){0.f, 0.f, 0.f, 0.f};
  f32x4* o4 = (f32x4*)out;
  f32x4* l4 = (f32x4*)Lbuf;
  for (int i = t; i < 262144 + 4096; i += 65536){
    if (i < 262144) o4[i] = z;
    else l4[i - 262144] = z;
  }
}

// ---------------------------------------------------------------------------
// Kernel 1: projections. grid (1024, 3), block 64 (1 wave per 16 rows).
// Pure-register 3-slot pipeline: slot = {2 f32x4 X frags + 4 short8 W frags}
// = 24 VGPR. Steady state: compute slot s (cc), immediately issue loads for
// cc+3 into s. ~18 loads in flight per wave; 12 waves/CU resident (grid
// 3072 = 12 blocks/CU, VGPR<=128 via launch_bounds). No LDS -> compiler
// emits counted vmcnt, no forced drains.
// ---------------------------------------------------------------------------
__global__ __launch_bounds__(64, 4) void proj_gemm(
    const float* __restrict__ Qx, const float* __restrict__ Kx, const float* __restrict__ Vx,
    const float* __restrict__ bqp, const float* __restrict__ bkp, const float* __restrict__ bvp,
    const unsigned short* __restrict__ Wp,
    unsigned short* __restrict__ qb, unsigned short* __restrict__ kb,
    unsigned short* __restrict__ vt)
{
  const int lane = threadIdx.x & 63;
  const int qd = lane >> 4, l = lane & 15;
  const int p = blockIdx.y;
  const float* X = (p == 0) ? Qx : ((p == 1) ? Kx : Vx);
  const float* bias = (p == 0) ? bqp : ((p == 1) ? bkp : bvp);
  const unsigned short* W = Wp + (size_t)p * 65536;

  const int row0 = blockIdx.x * 16;
  const float* xa = X + (size_t)(row0 + l) * 1024 + qd * 8;
  const unsigned short* wb = W + (size_t)lane * 8;

  f32x4 acc[4];
  #pragma unroll
  for (int nf = 0; nf < 4; ++nf) acc[nf] = (f32x4){0.f, 0.f, 0.f, 0.f};

  // 3 named pipeline slots (static indices only -- rule #20)
  f32x4 A_al, A_ah, B_al, B_ah, C_al, C_ah;
  short8 A_b0, A_b1, A_b2, A_b3;
  short8 B_b0, B_b1, B_b2, B_b3;
  short8 C_b0, C_b1, C_b2, C_b3;

#define XLD(S, CC) do{                                                         \
    S##_al = *(const f32x4*)(xa + (CC) * 32);                                  \
    S##_ah = *(const f32x4*)(xa + (CC) * 32 + 4);                              \
    const unsigned short* wc_ = wb + (size_t)(CC) * 2048;                      \
    S##_b0 = *(const short8*)(wc_);                                            \
    S##_b1 = *(const short8*)(wc_ + 512);                                      \
    S##_b2 = *(const short8*)(wc_ + 1024);                                     \
    S##_b3 = *(const short8*)(wc_ + 1536);                                     \
  } while (0)

#define CPSL(S) do{                                                            \
    short8 a_ = cvt8(S##_al, S##_ah);                                          \
    acc[0] = MFMA16x16x32(a_, S##_b0, acc[0]);                                 \
    acc[1] = MFMA16x16x32(a_, S##_b1, acc[1]);                                 \
    acc[2] = MFMA16x16x32(a_, S##_b2, acc[2]);                                 \
    acc[3] = MFMA16x16x32(a_, S##_b3, acc[3]);                                 \
  } while (0)

  XLD(A, 0);
  XLD(B, 1);
  XLD(C, 2);
  // steps 0..26 (9 groups of 3): compute cc, prefetch cc+3
  for (int i = 0; i < 27; i += 3){
    CPSL(A); XLD(A, i + 3);
    CPSL(B); XLD(B, i + 4);
    CPSL(C); XLD(C, i + 5);
  }
  // steps 27..31
  CPSL(A); XLD(A, 30);
  CPSL(B); XLD(B, 31);
  CPSL(C);
  CPSL(A);
  CPSL(B);
#undef XLD
#undef CPSL

  if (p == 2){
    int tg = row0 + qd * 4;
    int b = tg >> 12, tl = tg & 4095;
    #pragma unroll
    for (int nf = 0; nf < 4; ++nf){
      float bb = bias[nf * 16 + l];
      ushort4v pk;
      #pragma unroll
      for (int r = 0; r < 4; ++r) pk[r] = bf16u(acc[nf][r] + bb);
      *(ushort4v*)(vt + ((size_t)b * 64 + nf * 16 + l) * 4096 + tl) = pk;
    }
  } else {
    unsigned short* o = (p == 0) ? qb : kb;
    #pragma unroll
    for (int nf = 0; nf < 4; ++nf){
      float bb = bias[nf * 16 + l];
      #pragma unroll
      for (int r = 0; r < 4; ++r){
        int row = row0 + qd * 4 + r;
        o[(size_t)row * 64 + nf * 16 + l] = bf16u(acc[nf][r] + bb);
      }
    }
  }
}

// ---------------------------------------------------------------------------
// Kernel 2: split-KV causal flash, block-cooperative LDS staging.
// grid 1152 = 4 batches x 288 jobs; block 256 = 4 waves, wave w owns
// q-rows [qt*64 + w*16, +16). K/V 64-kv chunks double-buffered in LDS as
// distinct arrays (Ks0/Ks1, Vs0/Vs1), kv loop unrolled x2. (unchanged R4)
// ---------------------------------------------------------------------------
#define K1 0.18033688011112042f   // log2(e)/sqrt(64)

__global__ __launch_bounds__(256) void flash_split(
    const ushort* __restrict__ qb, const ushort* __restrict__ kb,
    const ushort* __restrict__ vt, float* __restrict__ out,
    float* __restrict__ Lbuf)
{
  __shared__ ushort Ks0[4096];    // [kvrow(64) * 64], 8 slots/row, c^(r&7)
  __shared__ ushort Ks1[4096];
  __shared__ ushort Vs0[4096];    // [d(64) * 64kv], 8 slots/row, c^(d&7)
  __shared__ ushort Vs1[4096];
  __shared__ ushort pbuf[4][16 * 40];

  const int tid = threadIdx.x;
  const int lane = tid & 63, wid = tid >> 6;
  const int qd = lane >> 4, l = lane & 15;
  const int lw = l & 7;

  // job decode (reversed: heavy groups first); batch = bidx&3 pins to 2 XCDs
  int bidx = (int)blockIdx.x;
  const int batch = bidx & 3;
  int j = 287 - (bidx >> 2);
  int g = 0;
  while (j >= 4 * (g + 1) * (g + 2)) ++g;        // g in 0..7
  int j2 = j - 4 * g * (g + 1);
  int tq = j2 / (g + 1);
  int s = j2 - tq * (g + 1);
  const int q0b = (8 * g + tq) * 64;
  const int kvstart = s * 512;
  const int kvend = min(kvstart + 512, q0b + 64); // width multiple of 64
  const int q0w = q0b + wid * 16;

  const ushort* kbB = kb + (size_t)batch * 262144;
  const ushort* vtB = vt + (size_t)batch * 262144;

  const ushort* qrow = qb + ((size_t)(batch * 4096 + q0w + l)) * 64 + qd * 8;
  short8 Qf0 = *(const short8*)(qrow);
  short8 Qf1 = *(const short8*)(qrow + 32);

  const f32x4 Zc = (f32x4){0.f, 0.f, 0.f, 0.f};
  f32x4 Oc[4] = {Zc, Zc, Zc, Zc};
  f32x4 Lacc = Zc;
  short8 onesf;
  #pragma unroll
  for (int i = 0; i < 8; ++i) onesf[i] = (short)0x3F80;   // bf16 1.0

  ushort* pw = &pbuf[wid][0];
  ushort* pwr = pw + qd * 160 + l;
  const ushort* prd = pw + l * 40 + qd * 8;

  // staging: wave w -> K rows {w*8..+7, 32+w*8..+7}, V d-rows same; lane maps
  // slot c=lane&7 of row r=(lane>>3): global col = (c ^ (r&7))*8
#define STAGE(KA, VA, KVC) do{                                                 \
    int r8_ = lane >> 3, sw_ = ((lane & 7) ^ r8_) << 3;                        \
    int rA_ = wid * 8 + r8_;                                                   \
    const ushort* gk_ = kbB + (size_t)((KVC) + rA_) * 64 + sw_;                \
    gl_lds16(gk_,            &(KA)[wid * 512]);                                \
    gl_lds16(gk_ + 32 * 64,  &(KA)[2048 + wid * 512]);                         \
    const ushort* gv_ = vtB + (size_t)rA_ * 4096 + (KVC) + sw_;                \
    gl_lds16(gv_,              &(VA)[wid * 512]);                              \
    gl_lds16(gv_ + 32 * 4096,  &(VA)[2048 + wid * 512]);                       \
  } while (0)

  // one 32-kv chunk: ROFF in {0,32} within the staged 64; KVG = global kv0
#define CHUNK(KA, VA, ROFF, KVG) do{                                           \
    if ((KVG) < q0w + 16){                                                     \
      const ushort* KsB_ = &(KA)[0];                                           \
      const ushort* VsB_ = &(VA)[0];                                           \
      short8 k0_ = *(const short8*)(KsB_ + (l + (ROFF)) * 64 + ((qd ^ lw) << 3));        \
      short8 k1_ = *(const short8*)(KsB_ + (l + (ROFF)) * 64 + (((qd + 4) ^ lw) << 3));  \
      short8 k2_ = *(const short8*)(KsB_ + (l + 16 + (ROFF)) * 64 + ((qd ^ lw) << 3));   \
      short8 k3_ = *(const short8*)(KsB_ + (l + 16 + (ROFF)) * 64 + (((qd + 4) ^ lw) << 3)); \
      f32x4 s0_ = MFMA16x16x32(Qf0, k0_, Zc);                                  \
      s0_ = MFMA16x16x32(Qf1, k1_, s0_);                                       \
      f32x4 s1_ = MFMA16x16x32(Qf0, k2_, Zc);                                  \
      s1_ = MFMA16x16x32(Qf1, k3_, s1_);                                       \
      float p0_[4], p1_[4];                                                    \
      _Pragma("unroll")                                                        \
      for (int r = 0; r < 4; ++r){                                             \
        p0_[r] = fast_exp2(s0_[r] * K1);                                       \
        p1_[r] = fast_exp2(s1_[r] * K1);                                       \
      }                                                                        \
      if ((KVG) + 31 > q0w){                                                   \
        _Pragma("unroll")                                                      \
        for (int r = 0; r < 4; ++r){                                           \
          int q_ = q0w + qd * 4 + r;                                           \
          if ((KVG) + l > q_) p0_[r] = 0.f;                                    \
          if ((KVG) + 16 + l > q_) p1_[r] = 0.f;                               \
        }                                                                      \
      }                                                                        \
      _Pragma("unroll")                                                        \
      for (int r = 0; r < 4; ++r){                                             \
        pwr[r * 40] = bf16u(p0_[r]);                                           \
        pwr[r * 40 + 16] = bf16u(p1_[r]);                                      \
      }                                                                        \
      short8 Pf_ = *(const short8*)(prd);                                      \
      int vs_ = ((qd + ((ROFF) >> 3)) ^ lw) << 3;                              \
      short8 v0_ = *(const short8*)(VsB_ + (l     ) * 64 + vs_);               \
      short8 v1_ = *(const short8*)(VsB_ + (l + 16) * 64 + vs_);               \
      short8 v2_ = *(const short8*)(VsB_ + (l + 32) * 64 + vs_);               \
      short8 v3_ = *(const short8*)(VsB_ + (l + 48) * 64 + vs_);               \
      Lacc = MFMA16x16x32(Pf_, onesf, Lacc);                                   \
      Oc[0] = MFMA16x16x32(Pf_, v0_, Oc[0]);                                   \
      Oc[1] = MFMA16x16x32(Pf_, v1_, Oc[1]);                                   \
      Oc[2] = MFMA16x16x32(Pf_, v2_, Oc[2]);                                   \
      Oc[3] = MFMA16x16x32(Pf_, v3_, Oc[3]);                                   \
    }                                                                          \
  } while (0)

  const int nst = (kvend - kvstart) >> 6;     // 64-kv stages (1..8)
  int kvc = kvstart;
  STAGE(Ks0, Vs0, kvc);
  __syncthreads();
  int it = 0;
  for (; it + 2 <= nst; it += 2){
    STAGE(Ks1, Vs1, kvc + 64);                 // async prefetch (distinct bufs)
    CHUNK(Ks0, Vs0, 0, kvc);
    CHUNK(Ks0, Vs0, 32, kvc + 32);
    __syncthreads();                           // drains prefetch + guards Ks0
    if (it + 2 < nst) STAGE(Ks0, Vs0, kvc + 128);
    CHUNK(Ks1, Vs1, 0, kvc + 64);
    CHUNK(Ks1, Vs1, 32, kvc + 96);
    __syncthreads();
    kvc += 128;
  }
  if (it < nst){                               // odd tail: chunk lives in Ks0
    CHUNK(Ks0, Vs0, 0, kvc);
    CHUNK(Ks0, Vs0, 32, kvc + 32);
  }
#undef STAGE
#undef CHUNK

  // accumulate partials
  float* ob = out + ((size_t)(batch * 4096 + q0w + qd * 4)) * 64 + l;
  #pragma unroll
  for (int nf = 0; nf < 4; ++nf)
    #pragma unroll
    for (int r = 0; r < 4; ++r)
      atomicAdd(&ob[(size_t)r * 64 + nf * 16], Oc[nf][r]);
  if (l == 0){
    float* lb = Lbuf + batch * 4096 + q0w + qd * 4;
    #pragma unroll
    for (int r = 0; r < 4; ++r) atomicAdd(&lb[r], Lacc[r]);
  }
}

// ---------------------------------------------------------------------------
// Kernel 3: out[row][d] /= L[row].
// ---------------------------------------------------------------------------
__global__ __launch_bounds__(256) void normalize(
    float* __restrict__ out, const float* __restrict__ Lbuf)
{
  int idx = blockIdx.x * 256 + threadIdx.x;
  f32x4 v = ((f32x4*)out)[idx];
  float inv = fast_rcp(Lbuf[idx >> 4]);
  v[0] *= inv; v[1] *= inv; v[2] *= inv; v[3] *= inv;
  ((f32x4*)out)[idx] = v;
}

// ---------------------------------------------------------------------------
extern "C" void kernel_launch(void* const* d_in, const int* in_sizes, int n_in,
                              void* d_out, int out_size, void* d_ws, size_t ws_size,
                              hipStream_t stream)
{
  const float* Q  = (const float*)d_in[0];
  const float* K  = (const float*)d_in[1];
  const float* V  = (const float*)d_in[2];
  const float* Wq = (const float*)d_in[3];
  const float* bq = (const float*)d_in[4];
  const float* Wk = (const float*)d_in[5];
  const float* bk = (const float*)d_in[6];
  const float* Wv = (const float*)d_in[7];
  const float* bv = (const float*)d_in[8];
  float* out = (float*)d_out;

  // workspace: qb(2MB) kb(2MB) vt(2MB) Wp(384KB) L(64KB)
  unsigned short* qb   = (unsigned short*)d_ws;
  unsigned short* kbuf = qb + (size_t)16384 * 64;
  unsigned short* vtp  = kbuf + (size_t)16384 * 64;
  unsigned short* Wp   = vtp + (size_t)16384 * 64;
  float* Lbuf = (float*)(Wp + (size_t)3 * 65536);

  pack_w<<<256, 256, 0, stream>>>(Wq, Wk, Wv, Wp, out, Lbuf);
  proj_gemm<<<dim3(1024, 3), 64, 0, stream>>>(Q, K, V, bq, bk, bv, Wp, qb, kbuf, vtp);
  flash_split<<<1152, 256, 0, stream>>>(qb, kbuf, vtp, out, Lbuf);
  normalize<<<1024, 256, 0, stream>>>(out, Lbuf);
}

// Round 4
// 249.167 us; speedup vs baseline: 1.0393x; 1.0393x over previous
//
#include <hip/hip_runtime.h>
#include <hip/hip_bf16.h>
#include <cstdint>
#include <cstddef>

// B=4, T=4096, C=1024, d=64 causal self-attention head.
// R7: proj_gemm = R0 body + split-K x2. Block 512 thr = 8 waves =
//   4 row-tiles x 2 K-halves; each wave runs the proven R0 inner loop over
//   half the C range; halves combine through a 16KB LDS exchange. Raises
//   resident waves/CU from 12 to 24 (the one structural cap every prior
//   variant shared). grid (256,3).
// pack_w / flash_split / normalize unchanged.

typedef __attribute__((ext_vector_type(8))) short short8;       // 8 x bf16 frag
typedef __attribute__((ext_vector_type(4))) float f32x4;
typedef __attribute__((ext_vector_type(4))) unsigned int uint4v;
typedef __attribute__((ext_vector_type(4))) unsigned short ushort4v;
typedef unsigned short ushort;

#define MFMA16x16x32(A,B,C) __builtin_amdgcn_mfma_f32_16x16x32_bf16((A),(B),(C),0,0,0)

static __device__ __forceinline__ unsigned pack2_bf16(float f0, float f1){
  unsigned u0 = __builtin_bit_cast(unsigned, f0) + 0x8000u;
  unsigned u1 = __builtin_bit_cast(unsigned, f1) + 0x8000u;
  return __builtin_amdgcn_perm(u1, u0, 0x07060302u);
}
static __device__ __forceinline__ unsigned short bf16u(float f){
  return (unsigned short)((__builtin_bit_cast(unsigned, f) + 0x8000u) >> 16);
}
static __device__ __forceinline__ short8 cvt8(f32x4 a, f32x4 b){
  union { unsigned u[4]; short8 s; } r;
  r.u[0] = pack2_bf16(a[0], a[1]);
  r.u[1] = pack2_bf16(a[2], a[3]);
  r.u[2] = pack2_bf16(b[0], b[1]);
  r.u[3] = pack2_bf16(b[2], b[3]);
  return r.s;
}
static __device__ __forceinline__ float fast_exp2(float x){
  float r; asm("v_exp_f32 %0, %1" : "=v"(r) : "v"(x)); return r;
}
static __device__ __forceinline__ float fast_rcp(float x){
  float r; asm("v_rcp_f32 %0, %1" : "=v"(r) : "v"(x)); return r;
}
static __device__ __forceinline__ void gl_lds16(const void* g, void* l){
  __builtin_amdgcn_global_load_lds(
      (const __attribute__((address_space(1))) void*)g,
      (__attribute__((address_space(3))) void*)l, 16, 0, 0);
}

// ---------------------------------------------------------------------------
// Kernel 0: pack W fp32 -> bf16 B-fragment layout; also zero out (4MB) + L.
// ---------------------------------------------------------------------------
__global__ __launch_bounds__(256) void pack_w(
    const float* __restrict__ Wq, const float* __restrict__ Wk,
    const float* __restrict__ Wv, unsigned short* __restrict__ Wp,
    float* __restrict__ out, float* __restrict__ Lbuf)
{
  int t = blockIdx.x * 256 + threadIdx.x;      // 256 blocks x 256 = 65536 thr
  if (t < 24576){                               // 3*32*4*64 pack jobs
    int lane = t & 63, nf = (t >> 6) & 3, cc = (t >> 8) & 31, p = t >> 13;
    int qd = lane >> 4, l = lane & 15;
    const float* W = (p == 0) ? Wq : ((p == 1) ? Wk : Wv);
    const float* src = W + (size_t)(cc * 32 + qd * 8) * 64 + nf * 16 + l;
    uint4v u;
    #pragma unroll
    for (int j = 0; j < 4; ++j)
      u[j] = pack2_bf16(src[(2 * j) * 64], src[(2 * j + 1) * 64]);
    *(uint4v*)(Wp + (size_t)t * 8) = u;
  }
  const f32x4 z = (f32x4){0.f, 0.f, 0.f, 0.f};
  f32x4* o4 = (f32x4*)out;
  f32x4* l4 = (f32x4*)Lbuf;
  for (int i = t; i < 262144 + 4096; i += 65536){
    if (i < 262144) o4[i] = z;
    else l4[i - 262144] = z;
  }
}

// ---------------------------------------------------------------------------
// Kernel 1: projections, split-K x2. grid (256, 3), block 512 (8 waves).
// wave wid: rt = wid>>1 (row-tile, 16 rows), kh = wid&1 (K-half).
// Inner loop identical to the proven R0 body, over cc in [kh*16, kh*16+16).
// kh=1 waves dump acc to LDS; kh=0 waves add + run the epilogue.
// 24 waves/CU resident (3 blocks x 8 waves) vs 12 in all prior variants.
// ---------------------------------------------------------------------------
__global__ __launch_bounds__(512, 6) void proj_gemm(
    const float* __restrict__ Qx, const float* __restrict__ Kx, const float* __restrict__ Vx,
    const float* __restrict__ bqp, const float* __restrict__ bkp, const float* __restrict__ bvp,
    const unsigned short* __restrict__ Wp,
    unsigned short* __restrict__ qb, unsigned short* __restrict__ kb,
    unsigned short* __restrict__ vt)
{
  __shared__ float cs[4][64][16];              // [rt][lane][nf*4+r], 16 KB

  const int tid = threadIdx.x;
  const int lane = tid & 63, wid = tid >> 6;   // wid 0..7
  const int kh = wid & 1, rt = wid >> 1;
  const int qd = lane >> 4, l = lane & 15;
  const int p = blockIdx.y;
  const float* X = (p == 0) ? Qx : ((p == 1) ? Kx : Vx);
  const float* bias = (p == 0) ? bqp : ((p == 1) ? bkp : bvp);
  const unsigned short* W = Wp + (size_t)p * 65536;

  const int row0 = blockIdx.x * 64 + rt * 16;
  const float* xa = X + (size_t)(row0 + l) * 1024 + qd * 8;
  const unsigned short* wb = W + (size_t)lane * 8;

  f32x4 acc[4];
  #pragma unroll
  for (int nf = 0; nf < 4; ++nf) acc[nf] = (f32x4){0.f, 0.f, 0.f, 0.f};

  const int cc0 = kh * 16;
  #pragma unroll 4
  for (int cc = cc0; cc < cc0 + 16; ++cc){
    f32x4 al = *(const f32x4*)(xa + cc * 32);
    f32x4 ah = *(const f32x4*)(xa + cc * 32 + 4);
    const unsigned short* wc = wb + (size_t)cc * 2048;
    short8 b0 = *(const short8*)(wc);
    short8 b1 = *(const short8*)(wc + 512);
    short8 b2 = *(const short8*)(wc + 1024);
    short8 b3 = *(const short8*)(wc + 1536);
    short8 a = cvt8(al, ah);
    acc[0] = MFMA16x16x32(a, b0, acc[0]);
    acc[1] = MFMA16x16x32(a, b1, acc[1]);
    acc[2] = MFMA16x16x32(a, b2, acc[2]);
    acc[3] = MFMA16x16x32(a, b3, acc[3]);
  }

  // combine the two K-halves through LDS
  if (kh == 1){
    float* dst = &cs[rt][lane][0];
    #pragma unroll
    for (int nf = 0; nf < 4; ++nf)
      *(f32x4*)(dst + nf * 4) = acc[nf];
  }
  __syncthreads();
  if (kh == 0){
    const float* src = &cs[rt][lane][0];
    #pragma unroll
    for (int nf = 0; nf < 4; ++nf){
      f32x4 o = *(const f32x4*)(src + nf * 4);
      acc[nf][0] += o[0]; acc[nf][1] += o[1];
      acc[nf][2] += o[2]; acc[nf][3] += o[3];
    }

    if (p == 2){
      int tg = row0 + qd * 4;
      int b = tg >> 12, tl = tg & 4095;
      #pragma unroll
      for (int nf = 0; nf < 4; ++nf){
        float bb = bias[nf * 16 + l];
        ushort4v pk;
        #pragma unroll
        for (int r = 0; r < 4; ++r) pk[r] = bf16u(acc[nf][r] + bb);
        *(ushort4v*)(vt + ((size_t)b * 64 + nf * 16 + l) * 4096 + tl) = pk;
      }
    } else {
      unsigned short* o = (p == 0) ? qb : kb;
      #pragma unroll
      for (int nf = 0; nf < 4; ++nf){
        float bb = bias[nf * 16 + l];
        #pragma unroll
        for (int r = 0; r < 4; ++r){
          int row = row0 + qd * 4 + r;
          o[(size_t)row * 64 + nf * 16 + l] = bf16u(acc[nf][r] + bb);
        }
      }
    }
  }
}

// ---------------------------------------------------------------------------
// Kernel 2: split-KV causal flash, block-cooperative LDS staging.
// grid 1152 = 4 batches x 288 jobs; block 256 = 4 waves, wave w owns
// q-rows [qt*64 + w*16, +16). K/V 64-kv chunks double-buffered in LDS as
// distinct arrays (Ks0/Ks1, Vs0/Vs1), kv loop unrolled x2. (unchanged)
// ---------------------------------------------------------------------------
#define K1 0.18033688011112042f   // log2(e)/sqrt(64)

__global__ __launch_bounds__(256) void flash_split(
    const ushort* __restrict__ qb, const ushort* __restrict__ kb,
    const ushort* __restrict__ vt, float* __restrict__ out,
    float* __restrict__ Lbuf)
{
  __shared__ ushort Ks0[4096];    // [kvrow(64) * 64], 8 slots/row, c^(r&7)
  __shared__ ushort Ks1[4096];
  __shared__ ushort Vs0[4096];    // [d(64) * 64kv], 8 slots/row, c^(d&7)
  __shared__ ushort Vs1[4096];
  __shared__ ushort pbuf[4][16 * 40];

  const int tid = threadIdx.x;
  const int lane = tid & 63, wid = tid >> 6;
  const int qd = lane >> 4, l = lane & 15;
  const int lw = l & 7;

  // job decode (reversed: heavy groups first); batch = bidx&3 pins to 2 XCDs
  int bidx = (int)blockIdx.x;
  const int batch = bidx & 3;
  int j = 287 - (bidx >> 2);
  int g = 0;
  while (j >= 4 * (g + 1) * (g + 2)) ++g;        // g in 0..7
  int j2 = j - 4 * g * (g + 1);
  int tq = j2 / (g + 1);
  int s = j2 - tq * (g + 1);
  const int q0b = (8 * g + tq) * 64;
  const int kvstart = s * 512;
  const int kvend = min(kvstart + 512, q0b + 64); // width multiple of 64
  const int q0w = q0b + wid * 16;

  const ushort* kbB = kb + (size_t)batch * 262144;
  const ushort* vtB = vt + (size_t)batch * 262144;

  const ushort* qrow = qb + ((size_t)(batch * 4096 + q0w + l)) * 64 + qd * 8;
  short8 Qf0 = *(const short8*)(qrow);
  short8 Qf1 = *(const short8*)(qrow + 32);

  const f32x4 Zc = (f32x4){0.f, 0.f, 0.f, 0.f};
  f32x4 Oc[4] = {Zc, Zc, Zc, Zc};
  f32x4 Lacc = Zc;
  short8 onesf;
  #pragma unroll
  for (int i = 0; i < 8; ++i) onesf[i] = (short)0x3F80;   // bf16 1.0

  ushort* pw = &pbuf[wid][0];
  ushort* pwr = pw + qd * 160 + l;
  const ushort* prd = pw + l * 40 + qd * 8;

  // staging: wave w -> K rows {w*8..+7, 32+w*8..+7}, V d-rows same; lane maps
  // slot c=lane&7 of row r=(lane>>3): global col = (c ^ (r&7))*8
#define STAGE(KA, VA, KVC) do{                                                 \
    int r8_ = lane >> 3, sw_ = ((lane & 7) ^ r8_) << 3;                        \
    int rA_ = wid * 8 + r8_;                                                   \
    const ushort* gk_ = kbB + (size_t)((KVC) + rA_) * 64 + sw_;                \
    gl_lds16(gk_,            &(KA)[wid * 512]);                                \
    gl_lds16(gk_ + 32 * 64,  &(KA)[2048 + wid * 512]);                         \
    const ushort* gv_ = vtB + (size_t)rA_ * 4096 + (KVC) + sw_;                \
    gl_lds16(gv_,              &(VA)[wid * 512]);                              \
    gl_lds16(gv_ + 32 * 4096,  &(VA)[2048 + wid * 512]);                       \
  } while (0)

  // one 32-kv chunk: ROFF in {0,32} within the staged 64; KVG = global kv0
#define CHUNK(KA, VA, ROFF, KVG) do{                                           \
    if ((KVG) < q0w + 16){                                                     \
      const ushort* KsB_ = &(KA)[0];                                           \
      const ushort* VsB_ = &(VA)[0];                                           \
      short8 k0_ = *(const short8*)(KsB_ + (l + (ROFF)) * 64 + ((qd ^ lw) << 3));        \
      short8 k1_ = *(const short8*)(KsB_ + (l + (ROFF)) * 64 + (((qd + 4) ^ lw) << 3));  \
      short8 k2_ = *(const short8*)(KsB_ + (l + 16 + (ROFF)) * 64 + ((qd ^ lw) << 3));   \
      short8 k3_ = *(const short8*)(KsB_ + (l + 16 + (ROFF)) * 64 + (((qd + 4) ^ lw) << 3)); \
      f32x4 s0_ = MFMA16x16x32(Qf0, k0_, Zc);                                  \
      s0_ = MFMA16x16x32(Qf1, k1_, s0_);                                       \
      f32x4 s1_ = MFMA16x16x32(Qf0, k2_, Zc);                                  \
      s1_ = MFMA16x16x32(Qf1, k3_, s1_);                                       \
      float p0_[4], p1_[4];                                                    \
      _Pragma("unroll")                                                        \
      for (int r = 0; r < 4; ++r){                                             \
        p0_[r] = fast_exp2(s0_[r] * K1);                                       \
        p1_[r] = fast_exp2(s1_[r] * K1);                                       \
      }                                                                        \
      if ((KVG) + 31 > q0w){                                                   \
        _Pragma("unroll")                                                      \
        for (int r = 0; r < 4; ++r){                                           \
          int q_ = q0w + qd * 4 + r;                                           \
          if ((KVG) + l > q_) p0_[r] = 0.f;                                    \
          if ((KVG) + 16 + l > q_) p1_[r] = 0.f;                               \
        }                                                                      \
      }                                                                        \
      _Pragma("unroll")                                                        \
      for (int r = 0; r < 4; ++r){                                             \
        pwr[r * 40] = bf16u(p0_[r]);                                           \
        pwr[r * 40 + 16] = bf16u(p1_[r]);                                      \
      }                                                                        \
      short8 Pf_ = *(const short8*)(prd);                                      \
      int vs_ = ((qd + ((ROFF) >> 3)) ^ lw) << 3;                              \
      short8 v0_ = *(const short8*)(VsB_ + (l     ) * 64 + vs_);               \
      short8 v1_ = *(const short8*)(VsB_ + (l + 16) * 64 + vs_);               \
      short8 v2_ = *(const short8*)(VsB_ + (l + 32) * 64 + vs_);               \
      short8 v3_ = *(const short8*)(VsB_ + (l + 48) * 64 + vs_);               \
      Lacc = MFMA16x16x32(Pf_, onesf, Lacc);                                   \
      Oc[0] = MFMA16x16x32(Pf_, v0_, Oc[0]);                                   \
      Oc[1] = MFMA16x16x32(Pf_, v1_, Oc[1]);                                   \
      Oc[2] = MFMA16x16x32(Pf_, v2_, Oc[2]);                                   \
      Oc[3] = MFMA16x16x32(Pf_, v3_, Oc[3]);                                   \
    }                                                                          \
  } while (0)

  const int nst = (kvend - kvstart) >> 6;     // 64-kv stages (1..8)
  int kvc = kvstart;
  STAGE(Ks0, Vs0, kvc);
  __syncthreads();
  int it = 0;
  for (; it + 2 <= nst; it += 2){
    STAGE(Ks1, Vs1, kvc + 64);                 // async prefetch (distinct bufs)
    CHUNK(Ks0, Vs0, 0, kvc);
    CHUNK(Ks0, Vs0, 32, kvc + 32);
    __syncthreads();                           // drains prefetch + guards Ks0
    if (it + 2 < nst) STAGE(Ks0, Vs0, kvc + 128);
    CHUNK(Ks1, Vs1, 0, kvc + 64);
    CHUNK(Ks1, Vs1, 32, kvc + 96);
    __syncthreads();
    kvc += 128;
  }
  if (it < nst){                               // odd tail: chunk lives in Ks0
    CHUNK(Ks0, Vs0, 0, kvc);
    CHUNK(Ks0, Vs0, 32, kvc + 32);
  }
#undef STAGE
#undef CHUNK

  // accumulate partials
  float* ob = out + ((size_t)(batch * 4096 + q0w + qd * 4)) * 64 + l;
  #pragma unroll
  for (int nf = 0; nf < 4; ++nf)
    #pragma unroll
    for (int r = 0; r < 4; ++r)
      atomicAdd(&ob[(size_t)r * 64 + nf * 16], Oc[nf][r]);
  if (l == 0){
    float* lb = Lbuf + batch * 4096 + q0w + qd * 4;
    #pragma unroll
    for (int r = 0; r < 4; ++r) atomicAdd(&lb[r], Lacc[r]);
  }
}

// ---------------------------------------------------------------------------
// Kernel 3: out[row][d] /= L[row].
// ---------------------------------------------------------------------------
__global__ __launch_bounds__(256) void normalize(
    float* __restrict__ out, const float* __restrict__ Lbuf)
{
  int idx = blockIdx.x * 256 + threadIdx.x;
  f32x4 v = ((f32x4*)out)[idx];
  float inv = fast_rcp(Lbuf[idx >> 4]);
  v[0] *= inv; v[1] *= inv; v[2] *= inv; v[3] *= inv;
  ((f32x4*)out)[idx] = v;
}

// ---------------------------------------------------------------------------
extern "C" void kernel_launch(void* const* d_in, const int* in_sizes, int n_in,
                              void* d_out, int out_size, void* d_ws, size_t ws_size,
                              hipStream_t stream)
{
  const float* Q  = (const float*)d_in[0];
  const float* K  = (const float*)d_in[1];
  const float* V  = (const float*)d_in[2];
  const float* Wq = (const float*)d_in[3];
  const float* bq = (const float*)d_in[4];
  const float* Wk = (const float*)d_in[5];
  const float* bk = (const float*)d_in[6];
  const float* Wv = (const float*)d_in[7];
  const float* bv = (const float*)d_in[8];
  float* out = (float*)d_out;

  // workspace: qb(2MB) kb(2MB) vt(2MB) Wp(384KB) L(64KB)
  unsigned short* qb   = (unsigned short*)d_ws;
  unsigned short* kbuf = qb + (size_t)16384 * 64;
  unsigned short* vtp  = kbuf + (size_t)16384 * 64;
  unsigned short* Wp   = vtp + (size_t)16384 * 64;
  float* Lbuf = (float*)(Wp + (size_t)3 * 65536);

  pack_w<<<256, 256, 0, stream>>>(Wq, Wk, Wv, Wp, out, Lbuf);
  proj_gemm<<<dim3(256, 3), 512, 0, stream>>>(Q, K, V, bq, bk, bv, Wp, qb, kbuf, vtp);
  flash_split<<<1152, 256, 0, stream>>>(qb, kbuf, vtp, out, Lbuf);
  normalize<<<1024, 256, 0, stream>>>(out, Lbuf);
}

// Round 5
// 248.104 us; speedup vs baseline: 1.0438x; 1.0043x over previous
//
#include <hip/hip_runtime.h>
#include <hip/hip_bf16.h>
#include <cstdint>
#include <cstddef>

// B=4, T=4096, C=1024, d=64 causal self-attention head.
// R8: proj_gemm X-read restructured for DRAM transaction efficiency.
//   Every prior variant (R0/R4/R6/R7, all ~78-90us) read X with 16 rows x
//   128B per wave-instruction (4KB stride) -- 16 scattered transactions.
//   Now: block=32 rows, X staged through LDS in 32-row x 1KB panels where
//   each global_load_lds covers 1KB CONTIGUOUS of one row (m13-shaped).
//   Lane-XOR swizzle within the 1KB span keeps fragment ds_read_b128s
//   conflict-free. Compute = proven R7 split-K body (2 row-tiles x 4-way
//   split-K, LDS combine). pack_w / flash_split / normalize unchanged.

typedef __attribute__((ext_vector_type(8))) short short8;       // 8 x bf16 frag
typedef __attribute__((ext_vector_type(4))) float f32x4;
typedef __attribute__((ext_vector_type(4))) unsigned int uint4v;
typedef __attribute__((ext_vector_type(4))) unsigned short ushort4v;
typedef unsigned short ushort;

#define MFMA16x16x32(A,B,C) __builtin_amdgcn_mfma_f32_16x16x32_bf16((A),(B),(C),0,0,0)

static __device__ __forceinline__ unsigned pack2_bf16(float f0, float f1){
  unsigned u0 = __builtin_bit_cast(unsigned, f0) + 0x8000u;
  unsigned u1 = __builtin_bit_cast(unsigned, f1) + 0x8000u;
  return __builtin_amdgcn_perm(u1, u0, 0x07060302u);
}
static __device__ __forceinline__ unsigned short bf16u(float f){
  return (unsigned short)((__builtin_bit_cast(unsigned, f) + 0x8000u) >> 16);
}
static __device__ __forceinline__ short8 cvt8(f32x4 a, f32x4 b){
  union { unsigned u[4]; short8 s; } r;
  r.u[0] = pack2_bf16(a[0], a[1]);
  r.u[1] = pack2_bf16(a[2], a[3]);
  r.u[2] = pack2_bf16(b[0], b[1]);
  r.u[3] = pack2_bf16(b[2], b[3]);
  return r.s;
}
static __device__ __forceinline__ float fast_exp2(float x){
  float r; asm("v_exp_f32 %0, %1" : "=v"(r) : "v"(x)); return r;
}
static __device__ __forceinline__ float fast_rcp(float x){
  float r; asm("v_rcp_f32 %0, %1" : "=v"(r) : "v"(x)); return r;
}
static __device__ __forceinline__ void gl_lds16(const void* g, void* l){
  __builtin_amdgcn_global_load_lds(
      (const __attribute__((address_space(1))) void*)g,
      (__attribute__((address_space(3))) void*)l, 16, 0, 0);
}

// ---------------------------------------------------------------------------
// Kernel 0: pack W fp32 -> bf16 B-fragment layout; also zero out (4MB) + L.
// ---------------------------------------------------------------------------
__global__ __launch_bounds__(256) void pack_w(
    const float* __restrict__ Wq, const float* __restrict__ Wk,
    const float* __restrict__ Wv, unsigned short* __restrict__ Wp,
    float* __restrict__ out, float* __restrict__ Lbuf)
{
  int t = blockIdx.x * 256 + threadIdx.x;      // 256 blocks x 256 = 65536 thr
  if (t < 24576){                               // 3*32*4*64 pack jobs
    int lane = t & 63, nf = (t >> 6) & 3, cc = (t >> 8) & 31, p = t >> 13;
    int qd = lane >> 4, l = lane & 15;
    const float* W = (p == 0) ? Wq : ((p == 1) ? Wk : Wv);
    const float* src = W + (size_t)(cc * 32 + qd * 8) * 64 + nf * 16 + l;
    uint4v u;
    #pragma unroll
    for (int j = 0; j < 4; ++j)
      u[j] = pack2_bf16(src[(2 * j) * 64], src[(2 * j + 1) * 64]);
    *(uint4v*)(Wp + (size_t)t * 8) = u;
  }
  const f32x4 z = (f32x4){0.f, 0.f, 0.f, 0.f};
  f32x4* o4 = (f32x4*)out;
  f32x4* l4 = (f32x4*)Lbuf;
  for (int i = t; i < 262144 + 4096; i += 65536){
    if (i < 262144) o4[i] = z;
    else l4[i - 262144] = z;
  }
}

// ---------------------------------------------------------------------------
// Kernel 1: projections. grid (512, 3), block 512 (8 waves), 32 rows/block.
// X staged via LDS: panel = 32 rows x 256 floats (32KB), double-buffered in
// DISTINCT arrays P0/P1. Each gl_lds = 1KB contiguous of ONE row (16B slots
// permuted by lane^(row&7); same 1KB span, so DRAM sees pure streaming).
// Reader: lane(l,qd) of wave(rt,kq) reads slots (s^c), s=lc*8+qd*2, c=l&7
// -> conflict-free b128. Waves: rt=wid>>2 (16-row tile), kq=wid&3 (K-quarter,
// cc = p*8 + kq*2 + i). 4-way combine through P0 after the panel loop.
// ---------------------------------------------------------------------------
__global__ __launch_bounds__(512, 4) void proj_gemm(
    const float* __restrict__ Qx, const float* __restrict__ Kx, const float* __restrict__ Vx,
    const float* __restrict__ bqp, const float* __restrict__ bkp, const float* __restrict__ bvp,
    const unsigned short* __restrict__ Wp,
    unsigned short* __restrict__ qb, unsigned short* __restrict__ kb,
    unsigned short* __restrict__ vt)
{
  __shared__ float P0[8192];                   // 32KB panel buffer 0
  __shared__ float P1[8192];                   // 32KB panel buffer 1

  const int tid = threadIdx.x;
  const int lane = tid & 63, wid = tid >> 6;   // wid 0..7
  const int kq = wid & 3, rt = wid >> 2;       // K-quarter, row-tile
  const int qd = lane >> 4, l = lane & 15;
  const int cw = l & 7;
  const int p = blockIdx.y;
  const float* X = (p == 0) ? Qx : ((p == 1) ? Kx : Vx);
  const float* bias = (p == 0) ? bqp : ((p == 1) ? bkp : bvp);
  const unsigned short* W = Wp + (size_t)p * 65536;

  const int row0b = blockIdx.x * 32;           // block's first row
  const float* Xblk = X + (size_t)row0b * 1024;
  const unsigned short* wb = W + (size_t)lane * 8;

  f32x4 acc[4];
  #pragma unroll
  for (int nf = 0; nf < 4; ++nf) acc[nf] = (f32x4){0.f, 0.f, 0.f, 0.f};

  // stage panel PP (floats [PP*256, PP*256+256) of each of the 32 rows).
  // wave wid stages rows wid*4..wid*4+3; one gl_lds = one row's 1KB,
  // global 16B slot (lane^(row&7)) -> LDS slot lane.
#define STAGEP(PB, PP) do{                                                     \
    _Pragma("unroll")                                                          \
    for (int r_ = 0; r_ < 4; ++r_){                                            \
      int rr_ = wid * 4 + r_;                                                  \
      const float* src_ = Xblk + (size_t)rr_ * 1024 + (PP) * 256               \
                          + ((lane ^ (rr_ & 7)) << 2);                         \
      gl_lds16(src_, (PB) + rr_ * 256);                                        \
    }                                                                          \
  } while (0)

  // compute this wave's 2 cc-slabs of panel PP from buffer PB
#define PCOMPP(PB, PP) do{                                                     \
    _Pragma("unroll")                                                          \
    for (int i_ = 0; i_ < 2; ++i_){                                            \
      int lc_ = kq * 2 + i_;                                                   \
      int cc_ = (PP) * 8 + lc_;                                                \
      const unsigned short* wc_ = wb + (size_t)cc_ * 2048;                     \
      short8 b0_ = *(const short8*)(wc_);                                      \
      short8 b1_ = *(const short8*)(wc_ + 512);                                \
      short8 b2_ = *(const short8*)(wc_ + 1024);                               \
      short8 b3_ = *(const short8*)(wc_ + 1536);                               \
      const float* rb_ = (PB) + (rt * 16 + l) * 256;                           \
      int s_ = lc_ * 8 + qd * 2;                                               \
      f32x4 al_ = *(const f32x4*)(rb_ + ((s_ ^ cw) << 2));                     \
      f32x4 ah_ = *(const f32x4*)(rb_ + (((s_ + 1) ^ cw) << 2));               \
      short8 a_ = cvt8(al_, ah_);                                              \
      acc[0] = MFMA16x16x32(a_, b0_, acc[0]);                                  \
      acc[1] = MFMA16x16x32(a_, b1_, acc[1]);                                  \
      acc[2] = MFMA16x16x32(a_, b2_, acc[2]);                                  \
      acc[3] = MFMA16x16x32(a_, b3_, acc[3]);                                  \
    }                                                                          \
  } while (0)

  STAGEP(P0, 0);
  __syncthreads();
  #pragma unroll
  for (int pp = 0; pp < 4; ++pp){
    const float* cur = (pp & 1) ? P1 : P0;
    float* nxt = (pp & 1) ? P0 : P1;
    if (pp < 3) STAGEP(nxt, pp + 1);
    PCOMPP(cur, pp);
    __syncthreads();
  }
#undef STAGEP
#undef PCOMPP

  // 4-way split-K combine through P0 (all panel reads are behind barriers)
  if (kq != 0){
    float* dst = P0 + ((size_t)(rt * 3 + (kq - 1)) * 64 + lane) * 16;
    #pragma unroll
    for (int nf = 0; nf < 4; ++nf)
      *(f32x4*)(dst + nf * 4) = acc[nf];
  }
  __syncthreads();
  if (kq == 0){
    #pragma unroll
    for (int j = 0; j < 3; ++j){
      const float* src = P0 + ((size_t)(rt * 3 + j) * 64 + lane) * 16;
      #pragma unroll
      for (int nf = 0; nf < 4; ++nf){
        f32x4 o = *(const f32x4*)(src + nf * 4);
        acc[nf][0] += o[0]; acc[nf][1] += o[1];
        acc[nf][2] += o[2]; acc[nf][3] += o[3];
      }
    }

    const int row0 = row0b + rt * 16;
    if (p == 2){
      int tg = row0 + qd * 4;
      int b = tg >> 12, tl = tg & 4095;
      #pragma unroll
      for (int nf = 0; nf < 4; ++nf){
        float bb = bias[nf * 16 + l];
        ushort4v pk;
        #pragma unroll
        for (int r = 0; r < 4; ++r) pk[r] = bf16u(acc[nf][r] + bb);
        *(ushort4v*)(vt + ((size_t)b * 64 + nf * 16 + l) * 4096 + tl) = pk;
      }
    } else {
      unsigned short* o = (p == 0) ? qb : kb;
      #pragma unroll
      for (int nf = 0; nf < 4; ++nf){
        float bb = bias[nf * 16 + l];
        #pragma unroll
        for (int r = 0; r < 4; ++r){
          int row = row0 + qd * 4 + r;
          o[(size_t)row * 64 + nf * 16 + l] = bf16u(acc[nf][r] + bb);
        }
      }
    }
  }
}

// ---------------------------------------------------------------------------
// Kernel 2: split-KV causal flash, block-cooperative LDS staging.
// grid 1152 = 4 batches x 288 jobs; block 256 = 4 waves, wave w owns
// q-rows [qt*64 + w*16, +16). K/V 64-kv chunks double-buffered in LDS as
// distinct arrays (Ks0/Ks1, Vs0/Vs1), kv loop unrolled x2. (unchanged)
// ---------------------------------------------------------------------------
#define K1 0.18033688011112042f   // log2(e)/sqrt(64)

__global__ __launch_bounds__(256) void flash_split(
    const ushort* __restrict__ qb, const ushort* __restrict__ kb,
    const ushort* __restrict__ vt, float* __restrict__ out,
    float* __restrict__ Lbuf)
{
  __shared__ ushort Ks0[4096];    // [kvrow(64) * 64], 8 slots/row, c^(r&7)
  __shared__ ushort Ks1[4096];
  __shared__ ushort Vs0[4096];    // [d(64) * 64kv], 8 slots/row, c^(d&7)
  __shared__ ushort Vs1[4096];
  __shared__ ushort pbuf[4][16 * 40];

  const int tid = threadIdx.x;
  const int lane = tid & 63, wid = tid >> 6;
  const int qd = lane >> 4, l = lane & 15;
  const int lw = l & 7;

  // job decode (reversed: heavy groups first); batch = bidx&3 pins to 2 XCDs
  int bidx = (int)blockIdx.x;
  const int batch = bidx & 3;
  int j = 287 - (bidx >> 2);
  int g = 0;
  while (j >= 4 * (g + 1) * (g + 2)) ++g;        // g in 0..7
  int j2 = j - 4 * g * (g + 1);
  int tq = j2 / (g + 1);
  int s = j2 - tq * (g + 1);
  const int q0b = (8 * g + tq) * 64;
  const int kvstart = s * 512;
  const int kvend = min(kvstart + 512, q0b + 64); // width multiple of 64
  const int q0w = q0b + wid * 16;

  const ushort* kbB = kb + (size_t)batch * 262144;
  const ushort* vtB = vt + (size_t)batch * 262144;

  const ushort* qrow = qb + ((size_t)(batch * 4096 + q0w + l)) * 64 + qd * 8;
  short8 Qf0 = *(const short8*)(qrow);
  short8 Qf1 = *(const short8*)(qrow + 32);

  const f32x4 Zc = (f32x4){0.f, 0.f, 0.f, 0.f};
  f32x4 Oc[4] = {Zc, Zc, Zc, Zc};
  f32x4 Lacc = Zc;
  short8 onesf;
  #pragma unroll
  for (int i = 0; i < 8; ++i) onesf[i] = (short)0x3F80;   // bf16 1.0

  ushort* pw = &pbuf[wid][0];
  ushort* pwr = pw + qd * 160 + l;
  const ushort* prd = pw + l * 40 + qd * 8;

  // staging: wave w -> K rows {w*8..+7, 32+w*8..+7}, V d-rows same; lane maps
  // slot c=lane&7 of row r=(lane>>3): global col = (c ^ (r&7))*8
#define STAGE(KA, VA, KVC) do{                                                 \
    int r8_ = lane >> 3, sw_ = ((lane & 7) ^ r8_) << 3;                        \
    int rA_ = wid * 8 + r8_;                                                   \
    const ushort* gk_ = kbB + (size_t)((KVC) + rA_) * 64 + sw_;                \
    gl_lds16(gk_,            &(KA)[wid * 512]);                                \
    gl_lds16(gk_ + 32 * 64,  &(KA)[2048 + wid * 512]);                         \
    const ushort* gv_ = vtB + (size_t)rA_ * 4096 + (KVC) + sw_;                \
    gl_lds16(gv_,              &(VA)[wid * 512]);                              \
    gl_lds16(gv_ + 32 * 4096,  &(VA)[2048 + wid * 512]);                       \
  } while (0)

  // one 32-kv chunk: ROFF in {0,32} within the staged 64; KVG = global kv0
#define CHUNK(KA, VA, ROFF, KVG) do{                                           \
    if ((KVG) < q0w + 16){                                                     \
      const ushort* KsB_ = &(KA)[0];                                           \
      const ushort* VsB_ = &(VA)[0];                                           \
      short8 k0_ = *(const short8*)(KsB_ + (l + (ROFF)) * 64 + ((qd ^ lw) << 3));        \
      short8 k1_ = *(const short8*)(KsB_ + (l + (ROFF)) * 64 + (((qd + 4) ^ lw) << 3));  \
      short8 k2_ = *(const short8*)(KsB_ + (l + 16 + (ROFF)) * 64 + ((qd ^ lw) << 3));   \
      short8 k3_ = *(const short8*)(KsB_ + (l + 16 + (ROFF)) * 64 + (((qd + 4) ^ lw) << 3)); \
      f32x4 s0_ = MFMA16x16x32(Qf0, k0_, Zc);                                  \
      s0_ = MFMA16x16x32(Qf1, k1_, s0_);                                       \
      f32x4 s1_ = MFMA16x16x32(Qf0, k2_, Zc);                                  \
      s1_ = MFMA16x16x32(Qf1, k3_, s1_);                                       \
      float p0_[4], p1_[4];                                                    \
      _Pragma("unroll")                                                        \
      for (int r = 0; r < 4; ++r){                                             \
        p0_[r] = fast_exp2(s0_[r] * K1);                                       \
        p1_[r] = fast_exp2(s1_[r] * K1);                                       \
      }                                                                        \
      if ((KVG) + 31 > q0w){                                                   \
        _Pragma("unroll")                                                      \
        for (int r = 0; r < 4; ++r){                                           \
          int q_ = q0w + qd * 4 + r;                                           \
          if ((KVG) + l > q_) p0_[r] = 0.f;                                    \
          if ((KVG) + 16 + l > q_) p1_[r] = 0.f;                               \
        }                                                                      \
      }                                                                        \
      _Pragma("unroll")                                                        \
      for (int r = 0; r < 4; ++r){                                             \
        pwr[r * 40] = bf16u(p0_[r]);                                           \
        pwr[r * 40 + 16] = bf16u(p1_[r]);                                      \
      }                                                                        \
      short8 Pf_ = *(const short8*)(prd);                                      \
      int vs_ = ((qd + ((ROFF) >> 3)) ^ lw) << 3;                              \
      short8 v0_ = *(const short8*)(VsB_ + (l     ) * 64 + vs_);               \
      short8 v1_ = *(const short8*)(VsB_ + (l + 16) * 64 + vs_);               \
      short8 v2_ = *(const short8*)(VsB_ + (l + 32) * 64 + vs_);               \
      short8 v3_ = *(const short8*)(VsB_ + (l + 48) * 64 + vs_);               \
      Lacc = MFMA16x16x32(Pf_, onesf, Lacc);                                   \
      Oc[0] = MFMA16x16x32(Pf_, v0_, Oc[0]);                                   \
      Oc[1] = MFMA16x16x32(Pf_, v1_, Oc[1]);                                   \
      Oc[2] = MFMA16x16x32(Pf_, v2_, Oc[2]);                                   \
      Oc[3] = MFMA16x16x32(Pf_, v3_, Oc[3]);                                   \
    }                                                                          \
  } while (0)

  const int nst = (kvend - kvstart) >> 6;     // 64-kv stages (1..8)
  int kvc = kvstart;
  STAGE(Ks0, Vs0, kvc);
  __syncthreads();
  int it = 0;
  for (; it + 2 <= nst; it += 2){
    STAGE(Ks1, Vs1, kvc + 64);                 // async prefetch (distinct bufs)
    CHUNK(Ks0, Vs0, 0, kvc);
    CHUNK(Ks0, Vs0, 32, kvc + 32);
    __syncthreads();                           // drains prefetch + guards Ks0
    if (it + 2 < nst) STAGE(Ks0, Vs0, kvc + 128);
    CHUNK(Ks1, Vs1, 0, kvc + 64);
    CHUNK(Ks1, Vs1, 32, kvc + 96);
    __syncthreads();
    kvc += 128;
  }
  if (it < nst){                               // odd tail: chunk lives in Ks0
    CHUNK(Ks0, Vs0, 0, kvc);
    CHUNK(Ks0, Vs0, 32, kvc + 32);
  }
#undef STAGE
#undef CHUNK

  // accumulate partials
  float* ob = out + ((size_t)(batch * 4096 + q0w + qd * 4)) * 64 + l;
  #pragma unroll
  for (int nf = 0; nf < 4; ++nf)
    #pragma unroll
    for (int r = 0; r < 4; ++r)
      atomicAdd(&ob[(size_t)r * 64 + nf * 16], Oc[nf][r]);
  if (l == 0){
    float* lb = Lbuf + batch * 4096 + q0w + qd * 4;
    #pragma unroll
    for (int r = 0; r < 4; ++r) atomicAdd(&lb[r], Lacc[r]);
  }
}

// ---------------------------------------------------------------------------
// Kernel 3: out[row][d] /= L[row].
// ---------------------------------------------------------------------------
__global__ __launch_bounds__(256) void normalize(
    float* __restrict__ out, const float* __restrict__ Lbuf)
{
  int idx = blockIdx.x * 256 + threadIdx.x;
  f32x4 v = ((f32x4*)out)[idx];
  float inv = fast_rcp(Lbuf[idx >> 4]);
  v[0] *= inv; v[1] *= inv; v[2] *= inv; v[3] *= inv;
  ((f32x4*)out)[idx] = v;
}

// ---------------------------------------------------------------------------
extern "C" void kernel_launch(void* const* d_in, const int* in_sizes, int n_in,
                              void* d_out, int out_size, void* d_ws, size_t ws_size,
                              hipStream_t stream)
{
  const float* Q  = (const float*)d_in[0];
  const float* K  = (const float*)d_in[1];
  const float* V  = (const float*)d_in[2];
  const float* Wq = (const float*)d_in[3];
  const float* bq = (const float*)d_in[4];
  const float* Wk = (const float*)d_in[5];
  const float* bk = (const float*)d_in[6];
  const float* Wv = (const float*)d_in[7];
  const float* bv = (const float*)d_in[8];
  float* out = (float*)d_out;

  // workspace: qb(2MB) kb(2MB) vt(2MB) Wp(384KB) L(64KB)
  unsigned short* qb   = (unsigned short*)d_ws;
  unsigned short* kbuf = qb + (size_t)16384 * 64;
  unsigned short* vtp  = kbuf + (size_t)16384 * 64;
  unsigned short* Wp   = vtp + (size_t)16384 * 64;
  float* Lbuf = (float*)(Wp + (size_t)3 * 65536);

  pack_w<<<256, 256, 0, stream>>>(Wq, Wk, Wv, Wp, out, Lbuf);
  proj_gemm<<<dim3(512, 3), 512, 0, stream>>>(Q, K, V, bq, bk, bv, Wp, qb, kbuf, vtp);
  flash_split<<<1152, 256, 0, stream>>>(qb, kbuf, vtp, out, Lbuf);
  normalize<<<1024, 256, 0, stream>>>(out, Lbuf);
}